// Round 2
// baseline (115.475 us; speedup 1.0000x reference)
//
#include <hip/hip_runtime.h>

typedef __attribute__((ext_vector_type(8))) short short8;
typedef __attribute__((ext_vector_type(4))) float f32x4;

#define NB_H 96
#define NB_W 128
#define NB_D 32
#define NB_C 16
#define NB_F 16

// fp32 -> bf16 round-to-nearest-even
static __device__ __forceinline__ unsigned short f2bf(float f) {
  unsigned int u = __builtin_bit_cast(unsigned int, f);
  unsigned int r = (u + 0x7fffu + ((u >> 16) & 1u)) >> 16;
  return (unsigned short)r;
}

__global__ __launch_bounds__(256) void sconv3d_mfma(
    const float* __restrict__ img, const int* __restrict__ bp,
    const float* __restrict__ kern, const float* __restrict__ dvp,
    float* __restrict__ out, int npix) {
  // ---- stage kernel weights to LDS as bf16, tap 27 zero-padded ----
  __shared__ unsigned short Kb[28 * 256];  // [tap][c][f]
  const int tid = threadIdx.x;
  for (int idx = tid; idx < 28 * 256; idx += 256) {
    unsigned short v = 0;
    if (idx < 27 * 256) v = f2bf(kern[idx]);
    Kb[idx] = v;
  }
  __syncthreads();

  const int lane = tid & 63;
  const int grp = lane >> 4;        // 0..3 (lane group)
  const int r = lane & 15;          // A: d-row low bits; B/D: f column
  const int c0 = (grp & 1) * 8;     // first c of this lane's 8-wide k-slice
  const int half = grp >> 1;        // 0 -> tap 2p, 1 -> tap 2p+1

  // ---- build B fragments (K[c][f] per tap-pair), kept in registers ----
  short8 bfrag[14];
#pragma unroll
  for (int p = 0; p < 14; ++p) {
#pragma unroll
    for (int j = 0; j < 8; ++j) {
      const int k = 8 * grp + j;            // 0..31
      const int t = 2 * p + (k >> 4);       // tap
      bfrag[p][j] = (short)Kb[t * 256 + (k & 15) * 16 + r];
    }
  }

  const int pix = blockIdx.x * 4 + (tid >> 6);
  if (pix >= npix) return;
  const int b = pix / (NB_H * NB_W);
  const int rem = pix - b * (NB_H * NB_W);
  const int h = rem >> 7;           // W=128
  const int w = rem & (NB_W - 1);

  const float dv = dvp[0];
  const int bpc = bp[pix];

  f32x4 acc0 = {0.f, 0.f, 0.f, 0.f};  // d-tile 0 (d = 0..15)
  f32x4 acc1 = {0.f, 0.f, 0.f, 0.f};  // d-tile 1 (d = 16..31)

#pragma unroll
  for (int p = 0; p < 14; ++p) {
    const int t = 2 * p + half;       // this lane's tap (27 == pad)
    const int n = t / 3;              // neighbor index 0..8 (9 for pad)
    const int kd = t - 3 * n;         // depth tap 0..2
    const int i = n / 3;
    const int j = n - 3 * i;
    const int hh = h + i - 1;
    const int ww = w + j - 1;
    const bool sv =
        (t < 27) && (hh >= 0) && (hh < NB_H) && (ww >= 0) && (ww < NB_W);
    const int hc = min(max(hh, 0), NB_H - 1);
    const int wc = min(max(ww, 0), NB_W - 1);
    const int nidx = (b * NB_H + hc) * NB_W + wc;
    const int rel = bpc - bp[nidx];
    const int base = nidx * (NB_D * NB_C);
    const int dsh = (kd - 1) + rel;   // d_src = d + dsh

    // ---- d-tile 0: d = r ----
    const int ds0 = r + dsh;
    short8 a0;
    {
      float va[8];
      if (sv && (ds0 >= 0) && (ds0 < NB_D)) {
        const float4* pp = (const float4*)(img + base + ds0 * NB_C + c0);
        const float4 x = pp[0];
        const float4 y = pp[1];
        va[0] = x.x; va[1] = x.y; va[2] = x.z; va[3] = x.w;
        va[4] = y.x; va[5] = y.y; va[6] = y.z; va[7] = y.w;
      } else {
#pragma unroll
        for (int q = 0; q < 8; ++q) va[q] = dv;
      }
#pragma unroll
      for (int q = 0; q < 8; ++q) a0[q] = (short)f2bf(va[q]);
    }
    acc0 = __builtin_amdgcn_mfma_f32_16x16x32_bf16(a0, bfrag[p], acc0, 0, 0, 0);

    // ---- d-tile 1: d = 16 + r ----
    const int ds1 = ds0 + 16;
    short8 a1;
    {
      float va[8];
      if (sv && (ds1 >= 0) && (ds1 < NB_D)) {
        const float4* pp = (const float4*)(img + base + ds1 * NB_C + c0);
        const float4 x = pp[0];
        const float4 y = pp[1];
        va[0] = x.x; va[1] = x.y; va[2] = x.z; va[3] = x.w;
        va[4] = y.x; va[5] = y.y; va[6] = y.z; va[7] = y.w;
      } else {
#pragma unroll
        for (int q = 0; q < 8; ++q) va[q] = dv;
      }
#pragma unroll
      for (int q = 0; q < 8; ++q) a1[q] = (short)f2bf(va[q]);
    }
    acc1 = __builtin_amdgcn_mfma_f32_16x16x32_bf16(a1, bfrag[p], acc1, 0, 0, 0);
  }

  // ---- write out: D lane layout col=lane&15 (=f), row=(lane>>4)*4+reg ----
  const int obase = pix * (NB_D * NB_F);
#pragma unroll
  for (int rr = 0; rr < 4; ++rr) {
    out[obase + (grp * 4 + rr) * NB_F + r] = acc0[rr];
    out[obase + (grp * 4 + rr + 16) * NB_F + r] = acc1[rr];
  }
}

extern "C" void kernel_launch(void* const* d_in, const int* in_sizes, int n_in,
                              void* d_out, int out_size, void* d_ws, size_t ws_size,
                              hipStream_t stream) {
  const float* img = (const float*)d_in[0];
  const int* bp = (const int*)d_in[1];
  const float* kern = (const float*)d_in[2];
  const float* dvp = (const float*)d_in[3];
  float* out = (float*)d_out;
  const int npix = 2 * NB_H * NB_W;  // 24576
  dim3 grid(npix / 4);
  sconv3d_mfma<<<grid, 256, 0, stream>>>(img, bp, kern, dvp, out, npix);
}

// Round 3
// 67.666 us; speedup vs baseline: 1.7065x; 1.7065x over previous
//
#include <hip/hip_runtime.h>

typedef __attribute__((ext_vector_type(8))) short short8;
typedef __attribute__((ext_vector_type(4))) float f32x4;

#define NB_H 96
#define NB_W 128
#define NB_D 32
#define NB_C 16
#define NB_F 16
#define NPIX (2 * NB_H * NB_W)                 // 24576
#define IMG_ELEMS (NPIX * NB_D * NB_C)         // 12,582,912
#define KB2_U16 (14 * 512)                     // 7168
#define WS_NEED ((size_t)IMG_ELEMS * 2 + (size_t)KB2_U16 * 2)

// fp32 -> bf16 round-to-nearest-even
static __device__ __forceinline__ unsigned short f2bf(float f) {
  unsigned int u = __builtin_bit_cast(unsigned int, f);
  unsigned int r = (u + 0x7fffu + ((u >> 16) & 1u)) >> 16;
  return (unsigned short)r;
}

// ---------------- pre-pass: fp32 image -> bf16, kernel -> B-frag layout ----
__global__ __launch_bounds__(256) void sconv3d_prepass(
    const float* __restrict__ img, const float* __restrict__ kern,
    unsigned short* __restrict__ wsb) {
  if (blockIdx.x < IMG_ELEMS / (256 * 8)) {
    const int i = (blockIdx.x * 256 + threadIdx.x) * 8;
    const float4 x = *(const float4*)(img + i);
    const float4 y = *(const float4*)(img + i + 4);
    short8 o;
    o[0] = (short)f2bf(x.x); o[1] = (short)f2bf(x.y);
    o[2] = (short)f2bf(x.z); o[3] = (short)f2bf(x.w);
    o[4] = (short)f2bf(y.x); o[5] = (short)f2bf(y.y);
    o[6] = (short)f2bf(y.z); o[7] = (short)f2bf(y.w);
    *(short8*)(wsb + i) = o;
  } else {
    // B-fragment-ordered bf16 weights: kb2[p*512 + f*32 + k] =
    //   bf16(kern[t][c][f]), t = 2p + (k>>4), c = k&15; tap 27 zero pad.
    unsigned short* kb2 = wsb + IMG_ELEMS;
    for (int i = threadIdx.x; i < KB2_U16; i += 256) {
      const int p = i >> 9;
      const int f = (i >> 5) & 15;
      const int k = i & 31;
      const int t = 2 * p + (k >> 4);
      const int c = k & 15;
      kb2[i] = (t < 27) ? f2bf(kern[(t * 16 + c) * 16 + f]) : (unsigned short)0;
    }
  }
}

// ---------------- main: one wave per pixel, 28 bf16 MFMAs, no LDS ----------
__global__ __launch_bounds__(256) void sconv3d_mfma_b(
    const unsigned short* __restrict__ imgb, const int* __restrict__ bp,
    const unsigned short* __restrict__ kb2, const float* __restrict__ dvp,
    float* __restrict__ out) {
  const int tid = threadIdx.x;
  const int lane = tid & 63;
  const int grp = lane >> 4;        // 0..3
  const int r = lane & 15;          // A: d row; B/D: f column
  const int c0 = (grp & 1) * 8;     // first c of this lane's 8-wide k-slice
  const int half = grp >> 1;        // 0 -> even tap, 1 -> odd tap

  short8 bfrag[14];
#pragma unroll
  for (int p = 0; p < 14; ++p)
    bfrag[p] = *(const short8*)(kb2 + p * 512 + r * 32 + grp * 8);

  const int pix = blockIdx.x * 4 + (tid >> 6);
  const int b = (pix >= NB_H * NB_W) ? 1 : 0;
  const int rem = pix - b * (NB_H * NB_W);
  const int h = rem >> 7;           // W = 128
  const int w = rem & (NB_W - 1);

  const unsigned short dvb = f2bf(dvp[0]);
  short8 dv8;
#pragma unroll
  for (int q = 0; q < 8; ++q) dv8[q] = (short)dvb;

  const int bpc = bp[pix];

  f32x4 acc0 = {0.f, 0.f, 0.f, 0.f};  // d = 0..15
  f32x4 acc1 = {0.f, 0.f, 0.f, 0.f};  // d = 16..31

#pragma unroll
  for (int p = 0; p < 14; ++p) {
    // tap decode: compile-time constants selected by `half`
    const int tE = 2 * p, tO = 2 * p + 1;
    const int di = (half ? tO / 9 : tE / 9) - 1;
    const int dj = (half ? (tO / 3) % 3 : (tE / 3) % 3) - 1;
    const int dk = (half ? tO % 3 : tE % 3) - 1;
    const bool pad = (half ? tO : tE) >= 27;

    const int hh = h + di;
    const int ww = w + dj;
    const bool sv = (!pad) && (hh >= 0) && (hh < NB_H) && (ww >= 0) && (ww < NB_W);
    const int hc = min(max(hh, 0), NB_H - 1);
    const int wc = min(max(ww, 0), NB_W - 1);
    const int nidx = (b * NB_H + hc) * NB_W + wc;
    const int rel = bpc - bp[nidx];
    const int dsh = dk + rel;
    const int base = nidx * (NB_D * NB_C);

    // d-tile 0: d = r
    const int ds0 = r + dsh;
    const bool v0 = sv && (ds0 >= 0) && (ds0 < NB_D);
    const int dc0 = min(max(ds0, 0), NB_D - 1);
    short8 a0 = *(const short8*)(imgb + base + dc0 * NB_C + c0);
    a0 = v0 ? a0 : dv8;
    acc0 = __builtin_amdgcn_mfma_f32_16x16x32_bf16(a0, bfrag[p], acc0, 0, 0, 0);

    // d-tile 1: d = 16 + r
    const int ds1 = ds0 + 16;
    const bool v1 = sv && (ds1 >= 0) && (ds1 < NB_D);
    const int dc1 = min(max(ds1, 0), NB_D - 1);
    short8 a1 = *(const short8*)(imgb + base + dc1 * NB_C + c0);
    a1 = v1 ? a1 : dv8;
    acc1 = __builtin_amdgcn_mfma_f32_16x16x32_bf16(a1, bfrag[p], acc1, 0, 0, 0);
  }

  // D layout: col = lane&15 (=f), row = grp*4 + reg
  const int obase = pix * (NB_D * NB_F);
#pragma unroll
  for (int rr = 0; rr < 4; ++rr) {
    out[obase + (grp * 4 + rr) * NB_F + r] = acc0[rr];
    out[obase + (grp * 4 + rr + 16) * NB_F + r] = acc1[rr];
  }
}

// ---------------- fallback (round-2 kernel) if ws is too small -------------
__global__ __launch_bounds__(256) void sconv3d_mfma(
    const float* __restrict__ img, const int* __restrict__ bp,
    const float* __restrict__ kern, const float* __restrict__ dvp,
    float* __restrict__ out, int npix) {
  __shared__ unsigned short Kb[28 * 256];
  const int tid = threadIdx.x;
  for (int idx = tid; idx < 28 * 256; idx += 256) {
    unsigned short v = 0;
    if (idx < 27 * 256) v = f2bf(kern[idx]);
    Kb[idx] = v;
  }
  __syncthreads();

  const int lane = tid & 63;
  const int grp = lane >> 4;
  const int r = lane & 15;
  const int c0 = (grp & 1) * 8;
  const int half = grp >> 1;

  short8 bfrag[14];
#pragma unroll
  for (int p = 0; p < 14; ++p) {
#pragma unroll
    for (int j = 0; j < 8; ++j) {
      const int k = 8 * grp + j;
      const int t = 2 * p + (k >> 4);
      bfrag[p][j] = (short)Kb[t * 256 + (k & 15) * 16 + r];
    }
  }

  const int pix = blockIdx.x * 4 + (tid >> 6);
  if (pix >= npix) return;
  const int b = pix / (NB_H * NB_W);
  const int rem = pix - b * (NB_H * NB_W);
  const int h = rem >> 7;
  const int w = rem & (NB_W - 1);

  const float dv = dvp[0];
  const int bpc = bp[pix];

  f32x4 acc0 = {0.f, 0.f, 0.f, 0.f};
  f32x4 acc1 = {0.f, 0.f, 0.f, 0.f};

#pragma unroll
  for (int p = 0; p < 14; ++p) {
    const int t = 2 * p + half;
    const int n = t / 3;
    const int kd = t - 3 * n;
    const int i = n / 3;
    const int j = n - 3 * i;
    const int hh = h + i - 1;
    const int ww = w + j - 1;
    const bool sv =
        (t < 27) && (hh >= 0) && (hh < NB_H) && (ww >= 0) && (ww < NB_W);
    const int hc = min(max(hh, 0), NB_H - 1);
    const int wc = min(max(ww, 0), NB_W - 1);
    const int nidx = (b * NB_H + hc) * NB_W + wc;
    const int rel = bpc - bp[nidx];
    const int base = nidx * (NB_D * NB_C);
    const int dsh = (kd - 1) + rel;

    const int ds0 = r + dsh;
    short8 a0;
    {
      float va[8];
      if (sv && (ds0 >= 0) && (ds0 < NB_D)) {
        const float4* pp = (const float4*)(img + base + ds0 * NB_C + c0);
        const float4 x = pp[0];
        const float4 y = pp[1];
        va[0] = x.x; va[1] = x.y; va[2] = x.z; va[3] = x.w;
        va[4] = y.x; va[5] = y.y; va[6] = y.z; va[7] = y.w;
      } else {
#pragma unroll
        for (int q = 0; q < 8; ++q) va[q] = dv;
      }
#pragma unroll
      for (int q = 0; q < 8; ++q) a0[q] = (short)f2bf(va[q]);
    }
    acc0 = __builtin_amdgcn_mfma_f32_16x16x32_bf16(a0, bfrag[p], acc0, 0, 0, 0);

    const int ds1 = ds0 + 16;
    short8 a1;
    {
      float va[8];
      if (sv && (ds1 >= 0) && (ds1 < NB_D)) {
        const float4* pp = (const float4*)(img + base + ds1 * NB_C + c0);
        const float4 x = pp[0];
        const float4 y = pp[1];
        va[0] = x.x; va[1] = x.y; va[2] = x.z; va[3] = x.w;
        va[4] = y.x; va[5] = y.y; va[6] = y.z; va[7] = y.w;
      } else {
#pragma unroll
        for (int q = 0; q < 8; ++q) va[q] = dv;
      }
#pragma unroll
      for (int q = 0; q < 8; ++q) a1[q] = (short)f2bf(va[q]);
    }
    acc1 = __builtin_amdgcn_mfma_f32_16x16x32_bf16(a1, bfrag[p], acc1, 0, 0, 0);
  }

  const int obase = pix * (NB_D * NB_F);
#pragma unroll
  for (int rr = 0; rr < 4; ++rr) {
    out[obase + (grp * 4 + rr) * NB_F + r] = acc0[rr];
    out[obase + (grp * 4 + rr + 16) * NB_F + r] = acc1[rr];
  }
}

extern "C" void kernel_launch(void* const* d_in, const int* in_sizes, int n_in,
                              void* d_out, int out_size, void* d_ws, size_t ws_size,
                              hipStream_t stream) {
  const float* img = (const float*)d_in[0];
  const int* bp = (const int*)d_in[1];
  const float* kern = (const float*)d_in[2];
  const float* dvp = (const float*)d_in[3];
  float* out = (float*)d_out;

  if (ws_size >= WS_NEED) {
    unsigned short* wsb = (unsigned short*)d_ws;
    const int img_blocks = IMG_ELEMS / (256 * 8);   // 6144
    sconv3d_prepass<<<img_blocks + 1, 256, 0, stream>>>(img, kern, wsb);
    sconv3d_mfma_b<<<NPIX / 4, 256, 0, stream>>>(wsb, bp, wsb + IMG_ELEMS, dvp, out);
  } else {
    sconv3d_mfma<<<NPIX / 4, 256, 0, stream>>>(img, bp, kern, dvp, out, NPIX);
  }
}